// Round 8
// baseline (133.973 us; speedup 1.0000x reference)
//
#include <hip/hip_runtime.h>
#include <hip/hip_bf16.h>
#include <cstdint>
#include <cstddef>
#include <math.h>

// Problem constants (reference: B=4096, D=256, T=0.5)
#define BSZ   4096
#define NROW  8192          // 2*B
#define DIM   256
#define INV_T 2.0f
#define EPS_N 1e-8f

typedef __attribute__((ext_vector_type(8))) short bf16x8;   // 8 bf16 = 4 VGPRs
typedef __attribute__((ext_vector_type(4))) float f32x4;

__device__ __forceinline__ unsigned short f2bf(float x) {
    __hip_bfloat16 h = __float2bfloat16(x);
    return __builtin_bit_cast(unsigned short, h);
}

// async global->LDS 16B helper (wave-uniform LDS base + lane*16 layout)
__device__ __forceinline__ void load_lds16(const void* g, void* l) {
    __builtin_amdgcn_global_load_lds(
        (const __attribute__((address_space(1))) void*)g,
        (__attribute__((address_space(3))) void*)l,
        16, 0, 0);
}

// ---------------------------------------------------------------------------
// zn2 staged layout (R5-verified, +6%): [strip(64)][kc(4)][row(128)][unit16(8)]
// with the XOR-swizzle baked in at write time:
//   zn2[s][kc][row][u] holds row bytes kc*128 + (u^(row&7))*16 .. +16
// => gram staging is pure sequential 16 KB streams; LDS image equals the
// verified swizzled layout; fragment-read side identical to R0.
//
// Kernel 1: row-normalize concat(z1,z2) into zn2 (R5 version, verified).
__global__ __launch_bounds__(256)
void nt_normalize(const float* __restrict__ z1,
                  const float* __restrict__ z2,
                  char* __restrict__ zn2,
                  float* __restrict__ rowsum) {
    const int wave = threadIdx.x >> 6;
    const int lane = threadIdx.x & 63;
    const int row  = blockIdx.x * 4 + wave;
    const float* src = (row < BSZ) ? (z1 + (size_t)row * DIM)
                                   : (z2 + (size_t)(row - BSZ) * DIM);
    const float4 v = ((const float4*)src)[lane];
    float ss = v.x * v.x + v.y * v.y + v.z * v.z + v.w * v.w;
    #pragma unroll
    for (int off = 32; off; off >>= 1) ss += __shfl_xor(ss, off);
    const float rinv = 1.0f / fmaxf(sqrtf(ss), EPS_N);  // torch eps clamp
    ushort4 o;
    o.x = f2bf(v.x * rinv);
    o.y = f2bf(v.y * rinv);
    o.z = f2bf(v.z * rinv);
    o.w = f2bf(v.w * rinv);
    // lane i holds row bytes [8i, 8i+8): kc=i>>4, unit=(i>>1)&7, half=i&1
    const int s    = row >> 7;
    const int lrow = row & 127;
    const int kc   = lane >> 4;
    const int unit = (lane >> 1) & 7;
    const int half = lane & 1;
    const int u    = unit ^ (lrow & 7);          // baked swizzle
    *(ushort4*)(zn2 + (size_t)s * 65536 + kc * 16384 + lrow * 128 + u * 16 + half * 8) = o;
    if (lane == 0) rowsum[row] = 0.0f;
}

// ---------------------------------------------------------------------------
// Kernel 2: tiled Zn·Znᵀ, upper triangle (2080 blocks), 128x128 tiles.
// ROUND CHANGE: 512 threads = 8 waves of 64x32 wave-tiles (acc = 32 VGPR),
// __launch_bounds__(512, 8) caps VGPR at 64 so FOUR blocks (32 waves) fit
// per CU vs R5's 20 waves. Theory: staging rate across R0-R7 tracks
// allocated waves at ~0.5 B/cyc/wave (R1/R6 16w -> 4.5-5.2; R0/R5/R2 20w ->
// 9.4-10.3; m13 copy 32w -> 24.6), independent of bytes/pattern/pipelining.
// 32 waves should lift the 128² structure (266 MB staged) from 43 to ~29 us.
// Staging source = R5's contiguous zn2 (verified); compute/epilogue = R7's
// 64x32 wave-tile math (verified on HW).
__global__ __launch_bounds__(512, 8)
void nt_gram(const char* __restrict__ zn2,
             float* __restrict__ rowsum,
             float* __restrict__ pos) {
    // Triangular decode: S(bi) = 64*bi - bi*(bi-1)/2 tiles before row bi.
    const int l = blockIdx.x;
    int bi = (int)((129.0 - sqrt(16641.0 - 8.0 * (double)l)) * 0.5);
    while (64 * (bi + 1) - (bi + 1) * bi / 2 <= l) ++bi;   // fp-edge correction
    while (64 * bi - bi * (bi - 1) / 2 > l) --bi;
    const int bj = bi + (l - (64 * bi - bi * (bi - 1) / 2));

    __shared__ char As[16384];   // [128 rows][128 B], swizzled image
    __shared__ char Bs[16384];

    const int t    = threadIdx.x;
    const int lane = t & 63;
    const int wave = t >> 6;
    const int wrow = (wave >> 2) * 64;   // 0,64
    const int wcol = (wave & 3) * 32;    // 0,32,64,96
    const int q    = lane >> 4;
    const int r16  = lane & 15;
    const int sw   = r16 & 7;            // read-side swizzle key
    const int t16  = t * 16;

    const char* A2 = zn2 + (size_t)bi * 65536;
    const char* B2 = zn2 + (size_t)bj * 65536;

    f32x4 acc[4][2] = {};

    for (int kc = 0; kc < 4; ++kc) {
        // Contiguous staging: 32 KB as four 8 KB sequential streams,
        // 4 loads/thread (512 threads x 16 B = 8192 B per load line).
        load_lds16(A2 + kc * 16384 + t16,        As + t16);
        load_lds16(A2 + kc * 16384 + 8192 + t16, As + 8192 + t16);
        load_lds16(B2 + kc * 16384 + t16,        Bs + t16);
        load_lds16(B2 + kc * 16384 + 8192 + t16, Bs + 8192 + t16);
        __syncthreads();

        #pragma unroll
        for (int kk = 0; kk < 64; kk += 32) {
            const int cpos = (((kk >> 3) + q) ^ sw) << 4;   // swizzled byte pos
            bf16x8 af[4], bfv[2];
            #pragma unroll
            for (int mi = 0; mi < 4; ++mi)
                af[mi] = *(const bf16x8*)(As + (wrow + mi * 16 + r16) * 128 + cpos);
            #pragma unroll
            for (int ni = 0; ni < 2; ++ni)
                bfv[ni] = *(const bf16x8*)(Bs + (wcol + ni * 16 + r16) * 128 + cpos);
            #pragma unroll
            for (int mi = 0; mi < 4; ++mi)
                #pragma unroll
                for (int ni = 0; ni < 2; ++ni)
                    acc[mi][ni] = __builtin_amdgcn_mfma_f32_16x16x32_bf16(
                        af[mi], bfv[ni], acc[mi][ni], 0, 0, 0);
        }
        __syncthreads();
    }

    // Epilogue (R7-verified 64x32 wave-tile version).
    // C/D layout: col=lane&15, row=(lane>>4)*4+reg (m89-verified).
    const bool diag_block = (bi == bj);
    float colp[2] = {0.f, 0.f};

    #pragma unroll
    for (int mi = 0; mi < 4; ++mi) {
        #pragma unroll
        for (int r = 0; r < 4; ++r) {
            const int grow = bi * 128 + wrow + mi * 16 + q * 4 + r;
            float s = 0.f;
            #pragma unroll
            for (int ni = 0; ni < 2; ++ni) {
                const int gcol = bj * 128 + wcol + ni * 16 + r16;
                const float val = acc[mi][ni][r];
                float e = __expf(val * INV_T);
                e = (grow == gcol) ? 0.f : e;   // exact diagonal exclusion
                s += e;
                colp[ni] += e;
                if (gcol == grow + BSZ) {       // positive pair (bj == bi+32)
                    pos[grow] = val;
                    pos[gcol] = val;            // symmetric partner
                }
            }
            s += __shfl_xor(s, 1);
            s += __shfl_xor(s, 2);
            s += __shfl_xor(s, 4);
            s += __shfl_xor(s, 8);
            if (r16 == 0) atomicAdd(&rowsum[grow], s);
        }
    }
    // Column sums -> bj strip rows (symmetry); skip on diagonal tiles.
    if (!diag_block) {
        #pragma unroll
        for (int ni = 0; ni < 2; ++ni) {
            float cs = colp[ni];
            cs += __shfl_xor(cs, 16);
            cs += __shfl_xor(cs, 32);
            if (q == 0) atomicAdd(&rowsum[bj * 128 + wcol + ni * 16 + r16], cs);
        }
    }
}

// ---------------------------------------------------------------------------
// Kernel 3: single block, 1024 threads, float4 loads (2 independent iters
// instead of an 8-deep dependent scalar chain); writes out[0] directly.
__global__ __launch_bounds__(1024)
void nt_finalize(const float* __restrict__ rowsum,
                 const float* __restrict__ pos,
                 float* __restrict__ out) {
    const float4* rs4 = (const float4*)rowsum;
    const float4* ps4 = (const float4*)pos;
    float v = 0.f;
    #pragma unroll
    for (int it = 0; it < 2; ++it) {
        const int i = it * 1024 + threadIdx.x;   // 2048 float4s = 8192 rows
        const float4 r = rs4[i];
        const float4 p = ps4[i];
        v += logf(__expf(p.x * INV_T) + r.x) - p.x * INV_T;
        v += logf(__expf(p.y * INV_T) + r.y) - p.y * INV_T;
        v += logf(__expf(p.z * INV_T) + r.z) - p.z * INV_T;
        v += logf(__expf(p.w * INV_T) + r.w) - p.w * INV_T;
    }
    #pragma unroll
    for (int off = 32; off; off >>= 1) v += __shfl_xor(v, off);
    __shared__ float redf[16];
    if ((threadIdx.x & 63) == 0) redf[threadIdx.x >> 6] = v;
    __syncthreads();
    if (threadIdx.x == 0) {
        float s = 0.f;
        #pragma unroll
        for (int w = 0; w < 16; ++w) s += redf[w];
        out[0] = s * (1.0f / NROW);
    }
}

// ---------------------------------------------------------------------------
extern "C" void kernel_launch(void* const* d_in, const int* in_sizes, int n_in,
                              void* d_out, int out_size, void* d_ws, size_t ws_size,
                              hipStream_t stream) {
    const float* z1 = (const float*)d_in[0];
    const float* z2 = (const float*)d_in[1];
    float* out = (float*)d_out;

    char*  zn2    = (char*)d_ws;                                      // 4 MB
    float* rowsum = (float*)((char*)d_ws + (size_t)NROW * DIM * 2);   // 32 KB
    float* pos    = rowsum + NROW;                                    // 32 KB

    nt_normalize<<<NROW / 4, 256, 0, stream>>>(z1, z2, zn2, rowsum);
    nt_gram<<<2080, 512, 0, stream>>>(zn2, rowsum, pos);
    nt_finalize<<<1, 1024, 0, stream>>>(rowsum, pos, out);
}

// Round 9
// 109.903 us; speedup vs baseline: 1.2190x; 1.2190x over previous
//
#include <hip/hip_runtime.h>
#include <hip/hip_bf16.h>
#include <cstdint>
#include <cstddef>
#include <math.h>

// Problem constants (reference: B=4096, D=256, T=0.5)
#define BSZ   4096
#define NROW  8192          // 2*B
#define DIM   256
#define INV_T 2.0f
#define EPS_N 1e-8f

typedef __attribute__((ext_vector_type(8))) short bf16x8;   // 8 bf16 = 4 VGPRs
typedef __attribute__((ext_vector_type(4))) float f32x4;

__device__ __forceinline__ unsigned short f2bf(float x) {
    __hip_bfloat16 h = __float2bfloat16(x);
    return __builtin_bit_cast(unsigned short, h);
}

// async global->LDS 16B helper (wave-uniform LDS base + lane*16 layout)
__device__ __forceinline__ void load_lds16(const void* g, void* l) {
    __builtin_amdgcn_global_load_lds(
        (const __attribute__((address_space(1))) void*)g,
        (__attribute__((address_space(3))) void*)l,
        16, 0, 0);
}

// ---------------------------------------------------------------------------
// zn2 staged layout (R5-verified, +6%): [strip(64)][kc(4)][row(128)][unit16(8)]
// with the XOR-swizzle baked in at write time:
//   zn2[s][kc][row][u] holds row bytes kc*128 + (u^(row&7))*16 .. +16
// => gram staging is pure sequential 16 KB streams; LDS image equals the
// verified swizzled layout; fragment-read side identical to R0.
//
// Kernel 1: row-normalize concat(z1,z2) into zn2 (R5 version, verified).
__global__ __launch_bounds__(256)
void nt_normalize(const float* __restrict__ z1,
                  const float* __restrict__ z2,
                  char* __restrict__ zn2,
                  float* __restrict__ rowsum) {
    const int wave = threadIdx.x >> 6;
    const int lane = threadIdx.x & 63;
    const int row  = blockIdx.x * 4 + wave;
    const float* src = (row < BSZ) ? (z1 + (size_t)row * DIM)
                                   : (z2 + (size_t)(row - BSZ) * DIM);
    const float4 v = ((const float4*)src)[lane];
    float ss = v.x * v.x + v.y * v.y + v.z * v.z + v.w * v.w;
    #pragma unroll
    for (int off = 32; off; off >>= 1) ss += __shfl_xor(ss, off);
    const float rinv = 1.0f / fmaxf(sqrtf(ss), EPS_N);  // torch eps clamp
    ushort4 o;
    o.x = f2bf(v.x * rinv);
    o.y = f2bf(v.y * rinv);
    o.z = f2bf(v.z * rinv);
    o.w = f2bf(v.w * rinv);
    // lane i holds row bytes [8i, 8i+8): kc=i>>4, unit=(i>>1)&7, half=i&1
    const int s    = row >> 7;
    const int lrow = row & 127;
    const int kc   = lane >> 4;
    const int unit = (lane >> 1) & 7;
    const int half = lane & 1;
    const int u    = unit ^ (lrow & 7);          // baked swizzle
    *(ushort4*)(zn2 + (size_t)s * 65536 + kc * 16384 + lrow * 128 + u * 16 + half * 8) = o;
    if (lane == 0) rowsum[row] = 0.0f;
}

// ---------------------------------------------------------------------------
// Kernel 2: tiled Zn·Znᵀ, upper triangle (2080 blocks), 128x128 tiles.
// ROUND CHANGE vs R5/R8: 1024 threads = 16 waves in a 4x4 grid of 32x32
// wave-tiles. acc[2][2] = 16 VGPR, fragments 16 -> ~50 VGPR total, which
// HONESTLY fits __launch_bounds__(1024, 8)'s 64-VGPR cap (R8's 64x32 tiles
// needed ~66+ and spilled: FETCH/WRITE ballooned +28 MB). 2 blocks/CU x 16
// waves = 32 waves/CU vs R5's 20 allocated / ~7 resident. Theory: the kernel
// is latency-idle because too few live waves; 8 waves/SIMD with 4x smaller
// per-wave phases should finally fill the gaps. Epilogue reduces via LDS
// (aliased into dead As) to halve global atomic lane-ops vs R5 despite the
// finer wave split (256/block = 532k total).
__global__ __launch_bounds__(1024, 8)
void nt_gram(const char* __restrict__ zn2,
             float* __restrict__ rowsum,
             float* __restrict__ pos) {
    // Triangular decode: S(bi) = 64*bi - bi*(bi-1)/2 tiles before row bi.
    const int l = blockIdx.x;
    int bi = (int)((129.0 - sqrt(16641.0 - 8.0 * (double)l)) * 0.5);
    while (64 * (bi + 1) - (bi + 1) * bi / 2 <= l) ++bi;   // fp-edge correction
    while (64 * bi - bi * (bi - 1) / 2 > l) --bi;
    const int bj = bi + (l - (64 * bi - bi * (bi - 1) / 2));

    __shared__ char As[16384];   // [128 rows][128 B], swizzled image
    __shared__ char Bs[16384];

    const int t    = threadIdx.x;
    const int lane = t & 63;
    const int wave = t >> 6;
    const int wrow = (wave >> 2) * 32;   // 0,32,64,96
    const int wcol = (wave & 3) * 32;    // 0,32,64,96
    const int q    = lane >> 4;
    const int r16  = lane & 15;
    const int sw   = r16 & 7;            // read-side swizzle key
    const int t16  = t * 16;

    const char* A2 = zn2 + (size_t)bi * 65536;
    const char* B2 = zn2 + (size_t)bj * 65536;

    f32x4 acc[2][2] = {};

    for (int kc = 0; kc < 4; ++kc) {
        // Contiguous staging: 1024 threads x 16 B = 16 KB per operand,
        // one load_lds16 per thread per operand (2 in flight per wave).
        load_lds16(A2 + kc * 16384 + t16, As + t16);
        load_lds16(B2 + kc * 16384 + t16, Bs + t16);
        __syncthreads();

        #pragma unroll
        for (int kk = 0; kk < 64; kk += 32) {
            const int cpos = (((kk >> 3) + q) ^ sw) << 4;   // swizzled byte pos
            bf16x8 af[2], bfv[2];
            #pragma unroll
            for (int mi = 0; mi < 2; ++mi)
                af[mi] = *(const bf16x8*)(As + (wrow + mi * 16 + r16) * 128 + cpos);
            #pragma unroll
            for (int ni = 0; ni < 2; ++ni)
                bfv[ni] = *(const bf16x8*)(Bs + (wcol + ni * 16 + r16) * 128 + cpos);
            #pragma unroll
            for (int mi = 0; mi < 2; ++mi)
                #pragma unroll
                for (int ni = 0; ni < 2; ++ni)
                    acc[mi][ni] = __builtin_amdgcn_mfma_f32_16x16x32_bf16(
                        af[mi], bfv[ni], acc[mi][ni], 0, 0, 0);
        }
        __syncthreads();
    }

    // Epilogue: As is dead -> alias LDS accumulators (rowacc[128]|colacc[128]).
    float* rowacc = (float*)As;
    float* colacc = (float*)(As + 512);
    if (t < 256) ((float*)As)[t] = 0.0f;
    __syncthreads();

    // C/D layout: col=lane&15, row=(lane>>4)*4+reg (m89-verified).
    const bool diag_block = (bi == bj);
    float colp[2] = {0.f, 0.f};

    #pragma unroll
    for (int mi = 0; mi < 2; ++mi) {
        #pragma unroll
        for (int r = 0; r < 4; ++r) {
            const int trow = wrow + mi * 16 + q * 4 + r;
            const int grow = bi * 128 + trow;
            float s = 0.f;
            #pragma unroll
            for (int ni = 0; ni < 2; ++ni) {
                const int gcol = bj * 128 + wcol + ni * 16 + r16;
                const float val = acc[mi][ni][r];
                float e = __expf(val * INV_T);
                e = (grow == gcol) ? 0.f : e;   // exact diagonal exclusion
                s += e;
                colp[ni] += e;
                if (gcol == grow + BSZ) {       // positive pair (bj == bi+32)
                    pos[grow] = val;
                    pos[gcol] = val;            // symmetric partner
                }
            }
            s += __shfl_xor(s, 1);
            s += __shfl_xor(s, 2);
            s += __shfl_xor(s, 4);
            s += __shfl_xor(s, 8);
            if (r16 == 0) atomicAdd(&rowacc[trow], s);   // LDS ds_add
        }
    }
    if (!diag_block) {   // diag tiles: col sums would double-count (symmetry)
        #pragma unroll
        for (int ni = 0; ni < 2; ++ni) {
            float cs = colp[ni];
            cs += __shfl_xor(cs, 16);
            cs += __shfl_xor(cs, 32);
            if (q == 0) atomicAdd(&colacc[wcol + ni * 16 + r16], cs);  // LDS
        }
    }
    __syncthreads();
    // 128 (or 256) global atomic lane-ops per block.
    if (t < 128) {
        atomicAdd(&rowsum[bi * 128 + t], rowacc[t]);
    } else if (t < 256 && !diag_block) {
        atomicAdd(&rowsum[bj * 128 + (t - 128)], colacc[t - 128]);
    }
}

// ---------------------------------------------------------------------------
// Kernel 3: single block, 1024 threads, float4 loads (R8-verified);
// writes out[0] directly.
__global__ __launch_bounds__(1024)
void nt_finalize(const float* __restrict__ rowsum,
                 const float* __restrict__ pos,
                 float* __restrict__ out) {
    const float4* rs4 = (const float4*)rowsum;
    const float4* ps4 = (const float4*)pos;
    float v = 0.f;
    #pragma unroll
    for (int it = 0; it < 2; ++it) {
        const int i = it * 1024 + threadIdx.x;   // 2048 float4s = 8192 rows
        const float4 r = rs4[i];
        const float4 p = ps4[i];
        v += logf(__expf(p.x * INV_T) + r.x) - p.x * INV_T;
        v += logf(__expf(p.y * INV_T) + r.y) - p.y * INV_T;
        v += logf(__expf(p.z * INV_T) + r.z) - p.z * INV_T;
        v += logf(__expf(p.w * INV_T) + r.w) - p.w * INV_T;
    }
    #pragma unroll
    for (int off = 32; off; off >>= 1) v += __shfl_xor(v, off);
    __shared__ float redf[16];
    if ((threadIdx.x & 63) == 0) redf[threadIdx.x >> 6] = v;
    __syncthreads();
    if (threadIdx.x == 0) {
        float s = 0.f;
        #pragma unroll
        for (int w = 0; w < 16; ++w) s += redf[w];
        out[0] = s * (1.0f / NROW);
    }
}

// ---------------------------------------------------------------------------
extern "C" void kernel_launch(void* const* d_in, const int* in_sizes, int n_in,
                              void* d_out, int out_size, void* d_ws, size_t ws_size,
                              hipStream_t stream) {
    const float* z1 = (const float*)d_in[0];
    const float* z2 = (const float*)d_in[1];
    float* out = (float*)d_out;

    char*  zn2    = (char*)d_ws;                                      // 4 MB
    float* rowsum = (float*)((char*)d_ws + (size_t)NROW * DIM * 2);   // 32 KB
    float* pos    = rowsum + NROW;                                    // 32 KB

    nt_normalize<<<NROW / 4, 256, 0, stream>>>(z1, z2, zn2, rowsum);
    nt_gram<<<2080, 1024, 0, stream>>>(zn2, rowsum, pos);
    nt_finalize<<<1, 1024, 0, stream>>>(rowsum, pos, out);
}

// Round 10
// 109.525 us; speedup vs baseline: 1.2232x; 1.0035x over previous
//
#include <hip/hip_runtime.h>
#include <hip/hip_bf16.h>
#include <cstdint>
#include <cstddef>
#include <math.h>

// Problem constants (reference: B=4096, D=256, T=0.5)
#define BSZ   4096
#define NROW  8192          // 2*B
#define DIM   256
#define INV_T 2.0f
#define EPS_N 1e-8f

typedef __attribute__((ext_vector_type(8))) short bf16x8;   // 8 bf16 = 4 VGPRs
typedef __attribute__((ext_vector_type(4))) float f32x4;

__device__ __forceinline__ unsigned short f2bf(float x) {
    __hip_bfloat16 h = __float2bfloat16(x);
    return __builtin_bit_cast(unsigned short, h);
}

// async global->LDS 16B helper (wave-uniform LDS base + lane*16 layout)
__device__ __forceinline__ void load_lds16(const void* g, void* l) {
    __builtin_amdgcn_global_load_lds(
        (const __attribute__((address_space(1))) void*)g,
        (__attribute__((address_space(3))) void*)l,
        16, 0, 0);
}

// ---------------------------------------------------------------------------
// zn2 staged layout (R5-verified): [strip(64)][kc(4)][row(128)][unit16(8)]
// with the XOR-swizzle baked in at write time:
//   zn2[s][kc][row][u] holds row bytes kc*128 + (u^(row&7))*16 .. +16
// => B staging is pure sequential 16 KB streams; the LDS image equals the
// verified swizzled layout. A-fragment reads use the SAME cpos algebra
// directly on zn2 (swizzle cancels: slot cc^sw holds chunk cc since
// row&7 == r16&7 == sw for fragment rows).
//
// Kernel 1: row-normalize concat(z1,z2) into zn2 (R5 version, verified).
__global__ __launch_bounds__(256)
void nt_normalize(const float* __restrict__ z1,
                  const float* __restrict__ z2,
                  char* __restrict__ zn2,
                  float* __restrict__ rowsum) {
    const int wave = threadIdx.x >> 6;
    const int lane = threadIdx.x & 63;
    const int row  = blockIdx.x * 4 + wave;
    const float* src = (row < BSZ) ? (z1 + (size_t)row * DIM)
                                   : (z2 + (size_t)(row - BSZ) * DIM);
    const float4 v = ((const float4*)src)[lane];
    float ss = v.x * v.x + v.y * v.y + v.z * v.z + v.w * v.w;
    #pragma unroll
    for (int off = 32; off; off >>= 1) ss += __shfl_xor(ss, off);
    const float rinv = 1.0f / fmaxf(sqrtf(ss), EPS_N);  // torch eps clamp
    ushort4 o;
    o.x = f2bf(v.x * rinv);
    o.y = f2bf(v.y * rinv);
    o.z = f2bf(v.z * rinv);
    o.w = f2bf(v.w * rinv);
    // lane i holds row bytes [8i, 8i+8): kc=i>>4, unit=(i>>1)&7, half=i&1
    const int s    = row >> 7;
    const int lrow = row & 127;
    const int kc   = lane >> 4;
    const int unit = (lane >> 1) & 7;
    const int half = lane & 1;
    const int u    = unit ^ (lrow & 7);          // baked swizzle
    *(ushort4*)(zn2 + (size_t)s * 65536 + kc * 16384 + lrow * 128 + u * 16 + half * 8) = o;
    if (lane == 0) rowsum[row] = 0.0f;
}

// ---------------------------------------------------------------------------
// Kernel 2: tiled Zn·Znᵀ, upper triangle (2080 blocks), 128x128 tiles, 256
// threads = 4 waves (2x2 of 64x64 wave-tiles) — R5's verified 43.3 us
// structure with ONE change (dual-pipe experiment):
//   B tile  -> LDS via global_load_lds DMA  (133 MB on the DMA path)
//   A frags -> registers via plain loads    (R2-verified mechanism, reg path)
// Theory: single-path rounds (R2 reg-only: 10.3 B/cyc/CU; R5 DMA-only:
// 10.0) both pin at the same ~10 B/cyc/CU per-CU service cap. If the two
// paths have independent budgets, halving each path's bytes overlaps them
// -> ~2x staging. If the cap is shared, time is unchanged — either way the
// result is decisive.
__global__ __launch_bounds__(256)
void nt_gram(const char* __restrict__ zn2,
             float* __restrict__ rowsum,
             float* __restrict__ pos) {
    // Triangular decode: S(bi) = 64*bi - bi*(bi-1)/2 tiles before row bi.
    const int l = blockIdx.x;
    int bi = (int)((129.0 - sqrt(16641.0 - 8.0 * (double)l)) * 0.5);
    while (64 * (bi + 1) - (bi + 1) * bi / 2 <= l) ++bi;   // fp-edge correction
    while (64 * bi - bi * (bi - 1) / 2 > l) --bi;
    const int bj = bi + (l - (64 * bi - bi * (bi - 1) / 2));

    __shared__ char Bs[16384];   // [128 rows][128 B], swizzled image (B only)

    const int t    = threadIdx.x;
    const int lane = t & 63;
    const int wave = t >> 6;
    const int wrow = (wave >> 1) * 64;
    const int wcol = (wave & 1) * 64;
    const int q    = lane >> 4;
    const int r16  = lane & 15;
    const int sw   = r16 & 7;                    // swizzle key (== row&7)
    const int t16  = t * 16;

    const char* A2 = zn2 + (size_t)bi * 65536;
    const char* B2 = zn2 + (size_t)bj * 65536;

    f32x4 acc[4][4] = {};

    for (int kc = 0; kc < 4; ++kc) {
        // B: contiguous LDS-DMA staging (16 KB as four 4 KB lines).
        #pragma unroll
        for (int p = 0; p < 4; ++p)
            load_lds16(B2 + kc * 16384 + p * 4096 + t16, Bs + p * 4096 + t16);

        // A: fragments straight to registers (reg path), issued while the
        // B-DMA is in flight. Swizzle cancels: slot cc^sw of row holds
        // chunk cc, so the address uses the same cpos as the LDS side.
        bf16x8 af[2][4];
        #pragma unroll
        for (int kh = 0; kh < 2; ++kh) {
            const int cpos = (((kh << 2) + q) ^ sw) << 4;
            #pragma unroll
            for (int mi = 0; mi < 4; ++mi)
                af[kh][mi] = *(const bf16x8*)(
                    A2 + kc * 16384 + (wrow + mi * 16 + r16) * 128 + cpos);
        }
        __syncthreads();   // drains B-DMA (and A loads) for all waves

        #pragma unroll
        for (int kh = 0; kh < 2; ++kh) {
            const int cpos = (((kh << 2) + q) ^ sw) << 4;
            bf16x8 bfv[4];
            #pragma unroll
            for (int ni = 0; ni < 4; ++ni)
                bfv[ni] = *(const bf16x8*)(Bs + (wcol + ni * 16 + r16) * 128 + cpos);
            #pragma unroll
            for (int mi = 0; mi < 4; ++mi)
                #pragma unroll
                for (int ni = 0; ni < 4; ++ni)
                    acc[mi][ni] = __builtin_amdgcn_mfma_f32_16x16x32_bf16(
                        af[kh][mi], bfv[ni], acc[mi][ni], 0, 0, 0);
        }
        __syncthreads();
    }

    // Epilogue (R5-exact). C/D layout: col=lane&15, row=(lane>>4)*4+reg.
    const int c = r16;
    const bool diag_block = (bi == bj);
    float colp[4] = {0.f, 0.f, 0.f, 0.f};

    #pragma unroll
    for (int mi = 0; mi < 4; ++mi) {
        #pragma unroll
        for (int r = 0; r < 4; ++r) {
            const int grow = bi * 128 + wrow + mi * 16 + q * 4 + r;
            float s = 0.f;
            #pragma unroll
            for (int ni = 0; ni < 4; ++ni) {
                const int gcol = bj * 128 + wcol + ni * 16 + c;
                const float val = acc[mi][ni][r];
                float e = __expf(val * INV_T);
                e = (grow == gcol) ? 0.f : e;   // exact diagonal exclusion
                s += e;
                colp[ni] += e;
                if (gcol == grow + BSZ) {       // positive pair (bj == bi+32)
                    pos[grow] = val;
                    pos[gcol] = val;            // symmetric partner
                }
            }
            s += __shfl_xor(s, 1);
            s += __shfl_xor(s, 2);
            s += __shfl_xor(s, 4);
            s += __shfl_xor(s, 8);
            if (c == 0) atomicAdd(&rowsum[grow], s);
        }
    }
    // Column sums -> bj strip rows (symmetry); skip on diagonal tiles.
    if (!diag_block) {
        #pragma unroll
        for (int ni = 0; ni < 4; ++ni) {
            float cs = colp[ni];
            cs += __shfl_xor(cs, 16);
            cs += __shfl_xor(cs, 32);
            if (q == 0) atomicAdd(&rowsum[bj * 128 + wcol + ni * 16 + c], cs);
        }
    }
}

// ---------------------------------------------------------------------------
// Kernel 3: single block, 1024 threads, float4 loads (R8/R9-verified);
// writes out[0] directly.
__global__ __launch_bounds__(1024)
void nt_finalize(const float* __restrict__ rowsum,
                 const float* __restrict__ pos,
                 float* __restrict__ out) {
    const float4* rs4 = (const float4*)rowsum;
    const float4* ps4 = (const float4*)pos;
    float v = 0.f;
    #pragma unroll
    for (int it = 0; it < 2; ++it) {
        const int i = it * 1024 + threadIdx.x;   // 2048 float4s = 8192 rows
        const float4 r = rs4[i];
        const float4 p = ps4[i];
        v += logf(__expf(p.x * INV_T) + r.x) - p.x * INV_T;
        v += logf(__expf(p.y * INV_T) + r.y) - p.y * INV_T;
        v += logf(__expf(p.z * INV_T) + r.z) - p.z * INV_T;
        v += logf(__expf(p.w * INV_T) + r.w) - p.w * INV_T;
    }
    #pragma unroll
    for (int off = 32; off; off >>= 1) v += __shfl_xor(v, off);
    __shared__ float redf[16];
    if ((threadIdx.x & 63) == 0) redf[threadIdx.x >> 6] = v;
    __syncthreads();
    if (threadIdx.x == 0) {
        float s = 0.f;
        #pragma unroll
        for (int w = 0; w < 16; ++w) s += redf[w];
        out[0] = s * (1.0f / NROW);
    }
}

// ---------------------------------------------------------------------------
extern "C" void kernel_launch(void* const* d_in, const int* in_sizes, int n_in,
                              void* d_out, int out_size, void* d_ws, size_t ws_size,
                              hipStream_t stream) {
    const float* z1 = (const float*)d_in[0];
    const float* z2 = (const float*)d_in[1];
    float* out = (float*)d_out;

    char*  zn2    = (char*)d_ws;                                      // 4 MB
    float* rowsum = (float*)((char*)d_ws + (size_t)NROW * DIM * 2);   // 32 KB
    float* pos    = rowsum + NROW;                                    // 32 KB

    nt_normalize<<<NROW / 4, 256, 0, stream>>>(z1, z2, zn2, rowsum);
    nt_gram<<<2080, 256, 0, stream>>>(zn2, rowsum, pos);
    nt_finalize<<<1, 1024, 0, stream>>>(rowsum, pos, out);
}

// Round 11
// 100.829 us; speedup vs baseline: 1.3287x; 1.0862x over previous
//
#include <hip/hip_runtime.h>
#include <hip/hip_bf16.h>
#include <cstdint>
#include <cstddef>
#include <math.h>

// Problem constants (reference: B=4096, D=256, T=0.5)
#define BSZ   4096
#define NROW  8192          // 2*B
#define DIM   256
#define INV_T 2.0f
#define EPS_N 1e-8f

typedef __attribute__((ext_vector_type(4))) float f32x4;

// async global->LDS 16B helper (wave-uniform LDS base + lane*16 layout)
__device__ __forceinline__ void load_lds16(const void* g, void* l) {
    __builtin_amdgcn_global_load_lds(
        (const __attribute__((address_space(1))) void*)g,
        (__attribute__((address_space(3))) void*)l,
        16, 0, 0);
}

// ---------------------------------------------------------------------------
// zn3 staged layout — fp8 e4m3 version of the R5-verified scheme:
//   [strip(64)][kc(4)][row(128)][slot8(8)] , 8-byte units, XOR swizzle baked:
//   zn3[s][kc][row][u] holds elements kc*64 + (u^(row&7))*8 .. +8  (1 B each)
// => gram staging is pure sequential 8 KB streams; fragment reads use
// slot = (kh*4+q) ^ (row&7), the exact half-scale analog of the verified
// bf16 b128 swizzle (2-way per 32-lane phase = free).
//
// Kernel 1: row-normalize concat(z1,z2) into fp8 zn3. One row/wave.
// v_cvt_pk_fp8_f32 on gfx950 emits OCP e4m3 — the format the fp8 MFMA eats.
__global__ __launch_bounds__(256)
void nt_normalize(const float* __restrict__ z1,
                  const float* __restrict__ z2,
                  char* __restrict__ zn3,
                  float* __restrict__ rowsum) {
    const int wave = threadIdx.x >> 6;
    const int lane = threadIdx.x & 63;
    const int row  = blockIdx.x * 4 + wave;
    const float* src = (row < BSZ) ? (z1 + (size_t)row * DIM)
                                   : (z2 + (size_t)(row - BSZ) * DIM);
    const float4 v = ((const float4*)src)[lane];
    float ss = v.x * v.x + v.y * v.y + v.z * v.z + v.w * v.w;
    #pragma unroll
    for (int off = 32; off; off >>= 1) ss += __shfl_xor(ss, off);
    const float rinv = 1.0f / fmaxf(sqrtf(ss), EPS_N);  // torch eps clamp
    // pack 4 normalized floats -> 4 fp8 bytes (RNE, OCP e4m3 on gfx950)
    int pk = 0;
    pk = __builtin_amdgcn_cvt_pk_fp8_f32(v.x * rinv, v.y * rinv, pk, false);
    pk = __builtin_amdgcn_cvt_pk_fp8_f32(v.z * rinv, v.w * rinv, pk, true);
    // lane i holds elements k = 4i..4i+3: kc=i>>4, slot8=(i>>1)&7, off=(i&1)*4
    const int s    = row >> 7;
    const int lrow = row & 127;
    const int kc   = lane >> 4;
    const int unit = (lane >> 1) & 7;
    const int off4 = (lane & 1) * 4;
    const int u    = unit ^ (lrow & 7);          // baked swizzle
    *(int*)(zn3 + (size_t)s * 32768 + kc * 8192 + lrow * 64 + u * 8 + off4) = pk;
    if (lane == 0) rowsum[row] = 0.0f;
}

// ---------------------------------------------------------------------------
// Kernel 2: tiled Zn·Znᵀ, upper triangle (2080 blocks), 128x128 tiles, 256
// threads = 4 waves (2x2 of 64x64 wave-tiles) — R5's verified 43.3 us
// structure with ONE change: operands staged/consumed as fp8 e4m3.
// Theory: total vector-memory throughput is pinned at ~10 B/cyc/CU across
// all 10 structures tried (path/wave/pattern/pipeline independent), so
// time = staged bytes / rate. fp8 halves staged bytes (266->133 MB) at
// IDENTICAL geometry, access pattern, and MFMA count (16x16x32 fp8 = same
// shape; C/D layout dtype-independent).
__global__ __launch_bounds__(256)
void nt_gram(const char* __restrict__ zn3,
             float* __restrict__ rowsum,
             float* __restrict__ pos) {
    // Triangular decode: S(bi) = 64*bi - bi*(bi-1)/2 tiles before row bi.
    const int l = blockIdx.x;
    int bi = (int)((129.0 - sqrt(16641.0 - 8.0 * (double)l)) * 0.5);
    while (64 * (bi + 1) - (bi + 1) * bi / 2 <= l) ++bi;   // fp-edge correction
    while (64 * bi - bi * (bi - 1) / 2 > l) --bi;
    const int bj = bi + (l - (64 * bi - bi * (bi - 1) / 2));

    __shared__ char As[8192];   // [128 rows][64 B], swizzled fp8 image
    __shared__ char Bs[8192];

    const int t    = threadIdx.x;
    const int lane = t & 63;
    const int wave = t >> 6;
    const int wrow = (wave >> 1) * 64;
    const int wcol = (wave & 1) * 64;
    const int q    = lane >> 4;
    const int r16  = lane & 15;
    const int sw   = r16 & 7;                    // swizzle key (== row&7)
    const int t16  = t * 16;

    const char* A2 = zn3 + (size_t)bi * 32768;
    const char* B2 = zn3 + (size_t)bj * 32768;

    f32x4 acc[4][4] = {};

    for (int kc = 0; kc < 4; ++kc) {
        // Contiguous staging: 8 KB per operand as two 4 KB lines.
        load_lds16(A2 + kc * 8192 + t16,        As + t16);
        load_lds16(A2 + kc * 8192 + 4096 + t16, As + 4096 + t16);
        load_lds16(B2 + kc * 8192 + t16,        Bs + t16);
        load_lds16(B2 + kc * 8192 + 4096 + t16, Bs + 4096 + t16);
        __syncthreads();

        #pragma unroll
        for (int kh = 0; kh < 2; ++kh) {         // two K=32 fp8 MFMAs per kc
            const int spos = (((kh << 2) + q) ^ sw) << 3;   // swizzled 8B slot
            long af[4], bfv[4];
            #pragma unroll
            for (int mi = 0; mi < 4; ++mi)
                af[mi] = *(const long*)(As + (wrow + mi * 16 + r16) * 64 + spos);
            #pragma unroll
            for (int ni = 0; ni < 4; ++ni)
                bfv[ni] = *(const long*)(Bs + (wcol + ni * 16 + r16) * 64 + spos);
            #pragma unroll
            for (int mi = 0; mi < 4; ++mi)
                #pragma unroll
                for (int ni = 0; ni < 4; ++ni)
                    acc[mi][ni] = __builtin_amdgcn_mfma_f32_16x16x32_fp8_fp8(
                        af[mi], bfv[ni], acc[mi][ni], 0, 0, 0);
        }
        __syncthreads();
    }

    // Epilogue (R5-exact). C/D layout: col=lane&15, row=(lane>>4)*4+reg.
    const int c = r16;
    const bool diag_block = (bi == bj);
    float colp[4] = {0.f, 0.f, 0.f, 0.f};

    #pragma unroll
    for (int mi = 0; mi < 4; ++mi) {
        #pragma unroll
        for (int r = 0; r < 4; ++r) {
            const int grow = bi * 128 + wrow + mi * 16 + q * 4 + r;
            float s = 0.f;
            #pragma unroll
            for (int ni = 0; ni < 4; ++ni) {
                const int gcol = bj * 128 + wcol + ni * 16 + c;
                const float val = acc[mi][ni][r];
                float e = __expf(val * INV_T);
                e = (grow == gcol) ? 0.f : e;   // exact diagonal exclusion
                s += e;
                colp[ni] += e;
                if (gcol == grow + BSZ) {       // positive pair (bj == bi+32)
                    pos[grow] = val;
                    pos[gcol] = val;            // symmetric partner
                }
            }
            s += __shfl_xor(s, 1);
            s += __shfl_xor(s, 2);
            s += __shfl_xor(s, 4);
            s += __shfl_xor(s, 8);
            if (c == 0) atomicAdd(&rowsum[grow], s);
        }
    }
    // Column sums -> bj strip rows (symmetry); skip on diagonal tiles.
    if (!diag_block) {
        #pragma unroll
        for (int ni = 0; ni < 4; ++ni) {
            float cs = colp[ni];
            cs += __shfl_xor(cs, 16);
            cs += __shfl_xor(cs, 32);
            if (q == 0) atomicAdd(&rowsum[bj * 128 + wcol + ni * 16 + c], cs);
        }
    }
}

// ---------------------------------------------------------------------------
// Kernel 3: single block, 1024 threads, float4 loads (R8/R9-verified);
// writes out[0] directly.
__global__ __launch_bounds__(1024)
void nt_finalize(const float* __restrict__ rowsum,
                 const float* __restrict__ pos,
                 float* __restrict__ out) {
    const float4* rs4 = (const float4*)rowsum;
    const float4* ps4 = (const float4*)pos;
    float v = 0.f;
    #pragma unroll
    for (int it = 0; it < 2; ++it) {
        const int i = it * 1024 + threadIdx.x;   // 2048 float4s = 8192 rows
        const float4 r = rs4[i];
        const float4 p = ps4[i];
        v += logf(__expf(p.x * INV_T) + r.x) - p.x * INV_T;
        v += logf(__expf(p.y * INV_T) + r.y) - p.y * INV_T;
        v += logf(__expf(p.z * INV_T) + r.z) - p.z * INV_T;
        v += logf(__expf(p.w * INV_T) + r.w) - p.w * INV_T;
    }
    #pragma unroll
    for (int off = 32; off; off >>= 1) v += __shfl_xor(v, off);
    __shared__ float redf[16];
    if ((threadIdx.x & 63) == 0) redf[threadIdx.x >> 6] = v;
    __syncthreads();
    if (threadIdx.x == 0) {
        float s = 0.f;
        #pragma unroll
        for (int w = 0; w < 16; ++w) s += redf[w];
        out[0] = s * (1.0f / NROW);
    }
}

// ---------------------------------------------------------------------------
extern "C" void kernel_launch(void* const* d_in, const int* in_sizes, int n_in,
                              void* d_out, int out_size, void* d_ws, size_t ws_size,
                              hipStream_t stream) {
    const float* z1 = (const float*)d_in[0];
    const float* z2 = (const float*)d_in[1];
    float* out = (float*)d_out;

    char*  zn3    = (char*)d_ws;                                      // 2 MB
    float* rowsum = (float*)((char*)d_ws + (size_t)NROW * DIM);       // 32 KB
    float* pos    = rowsum + NROW;                                    // 32 KB

    nt_normalize<<<NROW / 4, 256, 0, stream>>>(z1, z2, zn3, rowsum);
    nt_gram<<<2080, 256, 0, stream>>>(zn3, rowsum, pos);
    nt_finalize<<<1, 1024, 0, stream>>>(rowsum, pos, out);
}

// Round 13
// 94.792 us; speedup vs baseline: 1.4133x; 1.0637x over previous
//
#include <hip/hip_runtime.h>
#include <hip/hip_bf16.h>
#include <cstdint>
#include <cstddef>
#include <math.h>

// Problem constants (reference: B=4096, D=256, T=0.5)
#define BSZ   4096
#define NROW  8192          // 2*B
#define DIM   256
#define INV_T 2.0f
#define EPS_N 1e-8f

typedef __attribute__((ext_vector_type(4))) float f32x4;

// async global->LDS 16B helper (wave-uniform LDS base + lane*16 layout)
__device__ __forceinline__ void load_lds16(const void* g, void* l) {
    __builtin_amdgcn_global_load_lds(
        (const __attribute__((address_space(1))) void*)g,
        (__attribute__((address_space(3))) void*)l,
        16, 0, 0);
}

// ---------------------------------------------------------------------------
// zn3 staged layout (R11-verified fp8 e4m3):
//   [strip(64)][kc(4)][row(128)][slot8(8)], 8-byte units, XOR swizzle baked:
//   zn3[s][kc][row][u] holds elements kc*64 + (u^(row&7))*8 .. +8
//
// Kernel 1: row-normalize concat(z1,z2) into fp8 zn3 (R11-verified).
// Also resets the finalize ticket counter.
__global__ __launch_bounds__(256)
void nt_normalize(const float* __restrict__ z1,
                  const float* __restrict__ z2,
                  char* __restrict__ zn3,
                  unsigned int* __restrict__ cnt) {
    const int wave = threadIdx.x >> 6;
    const int lane = threadIdx.x & 63;
    const int row  = blockIdx.x * 4 + wave;
    const float* src = (row < BSZ) ? (z1 + (size_t)row * DIM)
                                   : (z2 + (size_t)(row - BSZ) * DIM);
    const float4 v = ((const float4*)src)[lane];
    float ss = v.x * v.x + v.y * v.y + v.z * v.z + v.w * v.w;
    #pragma unroll
    for (int off = 32; off; off >>= 1) ss += __shfl_xor(ss, off);
    const float rinv = 1.0f / fmaxf(sqrtf(ss), EPS_N);  // torch eps clamp
    int pk = 0;
    pk = __builtin_amdgcn_cvt_pk_fp8_f32(v.x * rinv, v.y * rinv, pk, false);
    pk = __builtin_amdgcn_cvt_pk_fp8_f32(v.z * rinv, v.w * rinv, pk, true);
    // lane i holds elements k = 4i..4i+3: kc=i>>4, slot8=(i>>1)&7, off=(i&1)*4
    const int s    = row >> 7;
    const int lrow = row & 127;
    const int kc   = lane >> 4;
    const int unit = (lane >> 1) & 7;
    const int off4 = (lane & 1) * 4;
    const int u    = unit ^ (lrow & 7);          // baked swizzle
    *(int*)(zn3 + (size_t)s * 32768 + kc * 8192 + lrow * 64 + u * 8 + off4) = pk;
    if (row == 0 && lane == 0) *cnt = 0;         // reset finalize ticket
}

// ---------------------------------------------------------------------------
// Kernel 2: tiled Zn·Znᵀ, upper triangle (2080 blocks), 128x128 tiles, 256
// threads = 4 waves (2x2 of 64x64 wave-tiles). Staging/compute = R11's
// verified fp8 version, UNCHANGED. Epilogue: ZERO global atomics — each
// wave stores its 64-wide half-sums to PRIVATE slots of part[row][128]:
//   row-side: part[grow][2*bj + wcol/64]   (sum over the wave's 64 cols)
//   col-side: part[gcol][2*bi + wrow/64]   (sum over the wave's 64 rows)
// R12 bug fixed: the two wcol halves previously collided in one slot —
// slots are now per-half (128/row), every slot written exactly once.
__global__ __launch_bounds__(256)
void nt_gram(const char* __restrict__ zn3,
             float* __restrict__ part,
             float* __restrict__ pos) {
    // Triangular decode: S(bi) = 64*bi - bi*(bi-1)/2 tiles before row bi.
    const int l = blockIdx.x;
    int bi = (int)((129.0 - sqrt(16641.0 - 8.0 * (double)l)) * 0.5);
    while (64 * (bi + 1) - (bi + 1) * bi / 2 <= l) ++bi;   // fp-edge correction
    while (64 * bi - bi * (bi - 1) / 2 > l) --bi;
    const int bj = bi + (l - (64 * bi - bi * (bi - 1) / 2));

    __shared__ char As[8192];   // [128 rows][64 B], swizzled fp8 image
    __shared__ char Bs[8192];

    const int t    = threadIdx.x;
    const int lane = t & 63;
    const int wave = t >> 6;
    const int wrow = (wave >> 1) * 64;
    const int wcol = (wave & 1) * 64;
    const int q    = lane >> 4;
    const int r16  = lane & 15;
    const int sw   = r16 & 7;                    // swizzle key (== row&7)
    const int t16  = t * 16;

    const char* A2 = zn3 + (size_t)bi * 32768;
    const char* B2 = zn3 + (size_t)bj * 32768;

    f32x4 acc[4][4] = {};

    for (int kc = 0; kc < 4; ++kc) {
        // Contiguous staging: 8 KB per operand as two 4 KB lines.
        load_lds16(A2 + kc * 8192 + t16,        As + t16);
        load_lds16(A2 + kc * 8192 + 4096 + t16, As + 4096 + t16);
        load_lds16(B2 + kc * 8192 + t16,        Bs + t16);
        load_lds16(B2 + kc * 8192 + 4096 + t16, Bs + 4096 + t16);
        __syncthreads();

        #pragma unroll
        for (int kh = 0; kh < 2; ++kh) {         // two K=32 fp8 MFMAs per kc
            const int spos = (((kh << 2) + q) ^ sw) << 3;   // swizzled 8B slot
            long af[4], bfv[4];
            #pragma unroll
            for (int mi = 0; mi < 4; ++mi)
                af[mi] = *(const long*)(As + (wrow + mi * 16 + r16) * 64 + spos);
            #pragma unroll
            for (int ni = 0; ni < 4; ++ni)
                bfv[ni] = *(const long*)(Bs + (wcol + ni * 16 + r16) * 64 + spos);
            #pragma unroll
            for (int mi = 0; mi < 4; ++mi)
                #pragma unroll
                for (int ni = 0; ni < 4; ++ni)
                    acc[mi][ni] = __builtin_amdgcn_mfma_f32_16x16x32_fp8_fp8(
                        af[mi], bfv[ni], acc[mi][ni], 0, 0, 0);
        }
        __syncthreads();
    }

    // Epilogue. C/D layout: col=lane&15, row=(lane>>4)*4+reg (m89-verified).
    const int c = r16;
    const bool diag_block = (bi == bj);
    const int rslot = 2 * bj + (wcol >> 6);      // row-side private slot
    const int cslot = 2 * bi + (wrow >> 6);      // col-side private slot
    float colp[4] = {0.f, 0.f, 0.f, 0.f};

    #pragma unroll
    for (int mi = 0; mi < 4; ++mi) {
        #pragma unroll
        for (int r = 0; r < 4; ++r) {
            const int grow = bi * 128 + wrow + mi * 16 + q * 4 + r;
            float s = 0.f;
            #pragma unroll
            for (int ni = 0; ni < 4; ++ni) {
                const int gcol = bj * 128 + wcol + ni * 16 + c;
                const float val = acc[mi][ni][r];
                float e = __expf(val * INV_T);
                e = (grow == gcol) ? 0.f : e;   // exact diagonal exclusion
                s += e;
                colp[ni] += e;
                if (gcol == grow + BSZ) {       // positive pair (bj == bi+32)
                    pos[grow] = val;
                    pos[gcol] = val;            // symmetric partner
                }
            }
            s += __shfl_xor(s, 1);
            s += __shfl_xor(s, 2);
            s += __shfl_xor(s, 4);
            s += __shfl_xor(s, 8);
            // Private half-slot: plain store, no atomic, no collision.
            if (c == 0) part[(size_t)grow * 128 + rslot] = s;
        }
    }
    // Col sums -> bj strip rows at this wave's private half-slot.
    if (!diag_block) {
        #pragma unroll
        for (int ni = 0; ni < 4; ++ni) {
            float cs = colp[ni];
            cs += __shfl_xor(cs, 16);
            cs += __shfl_xor(cs, 32);          // butterfly: wave total in all lanes
            if (q == 0)
                part[(size_t)(bj * 128 + wcol + ni * 16 + c) * 128 + cslot] = cs;
        }
    }
}

// ---------------------------------------------------------------------------
// Kernel 3: 64 blocks x 256 threads; block b reduces rows b*128..+127 of
// part[8192][128] (coalesced float4, 2 threads/row x 16 float4), computes
// per-row lse contribution, block-reduces; last block folds 64 block sums.
__global__ __launch_bounds__(256)
void nt_finalize(const float* __restrict__ part,
                 const float* __restrict__ pos,
                 float* __restrict__ blocksum,
                 unsigned int* __restrict__ cnt,
                 float* __restrict__ out) {
    const int b    = blockIdx.x;
    const int t    = threadIdx.x;
    const int lane = t & 63;
    const int row  = b * 128 + (t >> 1);
    const int half = t & 1;

    const float4* p4 = (const float4*)(part + (size_t)row * 128 + half * 64);
    float s = 0.f;
    #pragma unroll
    for (int j = 0; j < 16; ++j) {
        const float4 v = p4[j];
        s += v.x + v.y + v.z + v.w;
    }
    s += __shfl_xor(s, 1);                 // combine the two halves
    float contrib = 0.f;
    if (half == 0) {
        const float pl = pos[row] * INV_T;
        contrib = logf(__expf(pl) + s) - pl;
    }
    #pragma unroll
    for (int off = 32; off; off >>= 1) contrib += __shfl_xor(contrib, off);
    __shared__ float r4[4];
    __shared__ int   slast;
    if (lane == 0) r4[t >> 6] = contrib;
    __syncthreads();
    if (t == 0) {
        blocksum[b] = r4[0] + r4[1] + r4[2] + r4[3];
        __threadfence();
        slast = (atomicAdd(cnt, 1u) == 63u);
    }
    __syncthreads();
    if (slast && t < 64) {                 // last block: fold 64 block sums
        float v = atomicAdd(&blocksum[t], 0.0f);   // device-coherent read
        #pragma unroll
        for (int off = 32; off; off >>= 1) v += __shfl_xor(v, off);
        if (t == 0) out[0] = v * (1.0f / NROW);
    }
}

// ---------------------------------------------------------------------------
extern "C" void kernel_launch(void* const* d_in, const int* in_sizes, int n_in,
                              void* d_out, int out_size, void* d_ws, size_t ws_size,
                              hipStream_t stream) {
    const float* z1 = (const float*)d_in[0];
    const float* z2 = (const float*)d_in[1];
    float* out = (float*)d_out;

    // Workspace (ws is 256 MiB per the harness fill; we use ~6.03 MB):
    char*  zn3      = (char*)d_ws;                                   // 2 MB
    float* part     = (float*)((char*)d_ws + (size_t)2097152);       // 4 MB
    float* pos      = (float*)((char*)d_ws + (size_t)6291456);       // 32 KB
    float* blocksum = pos + NROW;                                    // 256 B
    unsigned int* cnt = (unsigned int*)(blocksum + 64);              // 4 B

    nt_normalize<<<NROW / 4, 256, 0, stream>>>(z1, z2, zn3, cnt);
    nt_gram<<<2080, 256, 0, stream>>>(zn3, part, pos);
    nt_finalize<<<64, 256, 0, stream>>>(part, pos, blocksum, cnt, out);
}

// Round 14
// 94.653 us; speedup vs baseline: 1.4154x; 1.0015x over previous
//
#include <hip/hip_runtime.h>
#include <hip/hip_bf16.h>
#include <cstdint>
#include <cstddef>
#include <math.h>

// Problem constants (reference: B=4096, D=256, T=0.5)
#define BSZ   4096
#define NROW  8192          // 2*B
#define DIM   256
#define INV_T 2.0f
#define EPS_N 1e-8f

typedef __attribute__((ext_vector_type(4))) float f32x4;

// async global->LDS 16B helper (wave-uniform LDS base + lane*16 layout)
__device__ __forceinline__ void load_lds16(const void* g, void* l) {
    __builtin_amdgcn_global_load_lds(
        (const __attribute__((address_space(1))) void*)g,
        (__attribute__((address_space(3))) void*)l,
        16, 0, 0);
}

#define VMWAIT(N) asm volatile("s_waitcnt vmcnt(" #N ")" ::: "memory")

// ---------------------------------------------------------------------------
// zn3 staged layout (R11/R13-verified fp8 e4m3):
//   [strip(64)][kc(4)][row(128)][slot8(8)], 8-byte units, XOR swizzle baked:
//   zn3[s][kc][row][u] holds elements kc*64 + (u^(row&7))*8 .. +8
//
// Kernel 1: row-normalize concat(z1,z2) into fp8 zn3 (R11-verified).
// Also resets the finalize ticket counter.
__global__ __launch_bounds__(256)
void nt_normalize(const float* __restrict__ z1,
                  const float* __restrict__ z2,
                  char* __restrict__ zn3,
                  unsigned int* __restrict__ cnt) {
    const int wave = threadIdx.x >> 6;
    const int lane = threadIdx.x & 63;
    const int row  = blockIdx.x * 4 + wave;
    const float* src = (row < BSZ) ? (z1 + (size_t)row * DIM)
                                   : (z2 + (size_t)(row - BSZ) * DIM);
    const float4 v = ((const float4*)src)[lane];
    float ss = v.x * v.x + v.y * v.y + v.z * v.z + v.w * v.w;
    #pragma unroll
    for (int off = 32; off; off >>= 1) ss += __shfl_xor(ss, off);
    const float rinv = 1.0f / fmaxf(sqrtf(ss), EPS_N);  // torch eps clamp
    int pk = 0;
    pk = __builtin_amdgcn_cvt_pk_fp8_f32(v.x * rinv, v.y * rinv, pk, false);
    pk = __builtin_amdgcn_cvt_pk_fp8_f32(v.z * rinv, v.w * rinv, pk, true);
    // lane i holds elements k = 4i..4i+3: kc=i>>4, slot8=(i>>1)&7, off=(i&1)*4
    const int s    = row >> 7;
    const int lrow = row & 127;
    const int kc   = lane >> 4;
    const int unit = (lane >> 1) & 7;
    const int off4 = (lane & 1) * 4;
    const int u    = unit ^ (lrow & 7);          // baked swizzle
    *(int*)(zn3 + (size_t)s * 32768 + kc * 8192 + lrow * 64 + u * 8 + off4) = pk;
    if (row == 0 && lane == 0) *cnt = 0;         // reset finalize ticket
}

// ---------------------------------------------------------------------------
// Kernel 2: tiled Zn·Znᵀ, upper triangle (2080 blocks), 128x128 tiles, 256
// threads = 4 waves (2x2 of 64x64 wave-tiles). R13's passing fp8 kernel with
// ONE change: kc-staging is DOUBLE-BUFFERED with counted vmcnt (T4) —
// stage kc+1 issued before compute kc, vmcnt(4) waits (never 0 mid-loop).
// Theory: at bf16 gram sat exactly on the staging-bytes roofline (43.3 us =
// 266 MB / 6.1 TB/s); fp8 halved bytes but returned only 6.4 us — the 4x
// per-block vmcnt(0) drain latency is now exposed. This removes it while
// keeping 32 KB LDS -> 5 blocks/CU (the occupancy class that sustains the
// ~10 B/cyc/CU rate; R3/R6's counted-vmcnt tests were confounded at 1-2
// blocks/CU). Barrier pattern is R6's proven-correct one.
__global__ __launch_bounds__(256)
void nt_gram(const char* __restrict__ zn3,
             float* __restrict__ part,
             float* __restrict__ pos) {
    // Triangular decode: S(bi) = 64*bi - bi*(bi-1)/2 tiles before row bi.
    const int l = blockIdx.x;
    int bi = (int)((129.0 - sqrt(16641.0 - 8.0 * (double)l)) * 0.5);
    while (64 * (bi + 1) - (bi + 1) * bi / 2 <= l) ++bi;   // fp-edge correction
    while (64 * bi - bi * (bi - 1) / 2 > l) --bi;
    const int bj = bi + (l - (64 * bi - bi * (bi - 1) / 2));

    __shared__ char lds[32768];   // buf0 | buf1; each: As 8 KB | Bs 8 KB

    const int t    = threadIdx.x;
    const int lane = t & 63;
    const int wave = t >> 6;
    const int wrow = (wave >> 1) * 64;
    const int wcol = (wave & 1) * 64;
    const int q    = lane >> 4;
    const int r16  = lane & 15;
    const int sw   = r16 & 7;                    // swizzle key (== row&7)
    const int t16  = t * 16;

    const char* A2 = zn3 + (size_t)bi * 32768;
    const char* B2 = zn3 + (size_t)bj * 32768;

    f32x4 acc[4][4] = {};

    // Stage kc into buf: 4 DMA loads/thread (A: 2x4KB lines, B: 2x4KB).
#define STAGE(kc, buf)                                                   \
    {                                                                    \
        char* d_ = lds + (buf) * 16384;                                  \
        load_lds16(A2 + (kc) * 8192 + t16,        d_ + t16);             \
        load_lds16(A2 + (kc) * 8192 + 4096 + t16, d_ + 4096 + t16);      \
        load_lds16(B2 + (kc) * 8192 + t16,        d_ + 8192 + t16);      \
        load_lds16(B2 + (kc) * 8192 + 4096 + t16, d_ + 12288 + t16);     \
    }

#define COMPUTE(buf)                                                     \
    {                                                                    \
        const char* As_ = lds + (buf) * 16384;                           \
        const char* Bs_ = As_ + 8192;                                    \
        _Pragma("unroll")                                                \
        for (int kh = 0; kh < 2; ++kh) {                                 \
            const int spos = (((kh << 2) + q) ^ sw) << 3;                \
            long af[4], bfv[4];                                          \
            _Pragma("unroll")                                            \
            for (int mi = 0; mi < 4; ++mi)                               \
                af[mi] = *(const long*)(As_ + (wrow + mi * 16 + r16) * 64 + spos); \
            _Pragma("unroll")                                            \
            for (int ni = 0; ni < 4; ++ni)                               \
                bfv[ni] = *(const long*)(Bs_ + (wcol + ni * 16 + r16) * 64 + spos); \
            _Pragma("unroll")                                            \
            for (int mi = 0; mi < 4; ++mi)                               \
                _Pragma("unroll")                                        \
                for (int ni = 0; ni < 4; ++ni)                           \
                    acc[mi][ni] = __builtin_amdgcn_mfma_f32_16x16x32_fp8_fp8( \
                        af[mi], bfv[ni], acc[mi][ni], 0, 0, 0);          \
        }                                                                \
    }

    // Ledger (per-wave outstanding DMA): 4,8 -> wait4 -> 8 -> wait4 -> 8
    // -> wait4 -> wait0. Counted waits keep one stage in flight across
    // every compute; no mid-loop drain.
    STAGE(0, 0)
    STAGE(1, 1)
    VMWAIT(4);
    __builtin_amdgcn_s_barrier();
    COMPUTE(0)
    __builtin_amdgcn_s_barrier();            // all waves done reading buf0
    __builtin_amdgcn_sched_barrier(0);
    STAGE(2, 0)
    VMWAIT(4);
    __builtin_amdgcn_s_barrier();
    COMPUTE(1)
    __builtin_amdgcn_s_barrier();            // all waves done reading buf1
    __builtin_amdgcn_sched_barrier(0);
    STAGE(3, 1)
    VMWAIT(4);
    __builtin_amdgcn_s_barrier();
    COMPUTE(0)
    VMWAIT(0);
    __builtin_amdgcn_s_barrier();
    COMPUTE(1)
#undef STAGE
#undef COMPUTE

    // Epilogue (R13-verified). C/D layout: col=lane&15, row=(lane>>4)*4+reg.
    const int c = r16;
    const bool diag_block = (bi == bj);
    const int rslot = 2 * bj + (wcol >> 6);      // row-side private slot
    const int cslot = 2 * bi + (wrow >> 6);      // col-side private slot
    float colp[4] = {0.f, 0.f, 0.f, 0.f};

    #pragma unroll
    for (int mi = 0; mi < 4; ++mi) {
        #pragma unroll
        for (int r = 0; r < 4; ++r) {
            const int grow = bi * 128 + wrow + mi * 16 + q * 4 + r;
            float s = 0.f;
            #pragma unroll
            for (int ni = 0; ni < 4; ++ni) {
                const int gcol = bj * 128 + wcol + ni * 16 + c;
                const float val = acc[mi][ni][r];
                float e = __expf(val * INV_T);
                e = (grow == gcol) ? 0.f : e;   // exact diagonal exclusion
                s += e;
                colp[ni] += e;
                if (gcol == grow + BSZ) {       // positive pair (bj == bi+32)
                    pos[grow] = val;
                    pos[gcol] = val;            // symmetric partner
                }
            }
            s += __shfl_xor(s, 1);
            s += __shfl_xor(s, 2);
            s += __shfl_xor(s, 4);
            s += __shfl_xor(s, 8);
            // Private half-slot: plain store, no atomic, no collision.
            if (c == 0) part[(size_t)grow * 128 + rslot] = s;
        }
    }
    // Col sums -> bj strip rows at this wave's private half-slot.
    if (!diag_block) {
        #pragma unroll
        for (int ni = 0; ni < 4; ++ni) {
            float cs = colp[ni];
            cs += __shfl_xor(cs, 16);
            cs += __shfl_xor(cs, 32);          // butterfly: wave total in all lanes
            if (q == 0)
                part[(size_t)(bj * 128 + wcol + ni * 16 + c) * 128 + cslot] = cs;
        }
    }
}

// ---------------------------------------------------------------------------
// Kernel 3: 64 blocks x 256 threads (R13-verified); block b reduces rows
// b*128..+127 of part[8192][128], per-row lse contribution, block-reduce;
// last block (ticket) folds the 64 block sums.
__global__ __launch_bounds__(256)
void nt_finalize(const float* __restrict__ part,
                 const float* __restrict__ pos,
                 float* __restrict__ blocksum,
                 unsigned int* __restrict__ cnt,
                 float* __restrict__ out) {
    const int b    = blockIdx.x;
    const int t    = threadIdx.x;
    const int lane = t & 63;
    const int row  = b * 128 + (t >> 1);
    const int half = t & 1;

    const float4* p4 = (const float4*)(part + (size_t)row * 128 + half * 64);
    float s = 0.f;
    #pragma unroll
    for (int j = 0; j < 16; ++j) {
        const float4 v = p4[j];
        s += v.x + v.y + v.z + v.w;
    }
    s += __shfl_xor(s, 1);                 // combine the two halves
    float contrib = 0.f;
    if (half == 0) {
        const float pl = pos[row] * INV_T;
        contrib = logf(__expf(pl) + s) - pl;
    }
    #pragma unroll
    for (int off = 32; off; off >>= 1) contrib += __shfl_xor(contrib, off);
    __shared__ float r4[4];
    __shared__ int   slast;
    if (lane == 0) r4[t >> 6] = contrib;
    __syncthreads();
    if (t == 0) {
        blocksum[b] = r4[0] + r4[1] + r4[2] + r4[3];
        __threadfence();
        slast = (atomicAdd(cnt, 1u) == 63u);
    }
    __syncthreads();
    if (slast && t < 64) {                 // last block: fold 64 block sums
        float v = atomicAdd(&blocksum[t], 0.0f);   // device-coherent read
        #pragma unroll
        for (int off = 32; off; off >>= 1) v += __shfl_xor(v, off);
        if (t == 0) out[0] = v * (1.0f / NROW);
    }
}

// ---------------------------------------------------------------------------
extern "C" void kernel_launch(void* const* d_in, const int* in_sizes, int n_in,
                              void* d_out, int out_size, void* d_ws, size_t ws_size,
                              hipStream_t stream) {
    const float* z1 = (const float*)d_in[0];
    const float* z2 = (const float*)d_in[1];
    float* out = (float*)d_out;

    // Workspace (~6.03 MB of the 256 MiB ws):
    char*  zn3      = (char*)d_ws;                                   // 2 MB
    float* part     = (float*)((char*)d_ws + (size_t)2097152);       // 4 MB
    float* pos      = (float*)((char*)d_ws + (size_t)6291456);       // 32 KB
    float* blocksum = pos + NROW;                                    // 256 B
    unsigned int* cnt = (unsigned int*)(blocksum + 64);              // 4 B

    nt_normalize<<<NROW / 4, 256, 0, stream>>>(z1, z2, zn3, cnt);
    nt_gram<<<2080, 256, 0, stream>>>(zn3, part, pos);
    nt_finalize<<<64, 256, 0, stream>>>(part, pos, blocksum, cnt, out);
}